// Round 11
// baseline (862.207 us; speedup 1.0000x reference)
//
#include <hip/hip_runtime.h>
#include <hip/hip_bf16.h>
#include <stdint.h>

#define E_ 8
#define H_ 4096
#define I_ 1792
#define TWOI_ 3584
#define T_ 4096
#define NSLOT_ 8192
#define NRBMAX_ 40        /* max padded 256-slot blocks */
#define NS1_ 128          /* H_/32 k-slices */
#define NS2_ 56           /* I_/32 k-slices */
#define XGBLK_ 1048576    /* shorts per xg slot-block: 128*4*256*8 */
#define HPBLK_ 458752     /* shorts per h_pk slot-block: 56*4*256*8 */

typedef __attribute__((ext_vector_type(4))) float f32x4;
typedef __attribute__((ext_vector_type(8))) short bf16x8;

static __device__ __forceinline__ short f2bf(float f) {
    unsigned u = __builtin_bit_cast(unsigned, f);
    u += 0x7FFF + ((u >> 16) & 1);   // round-to-nearest-even
    return (short)(u >> 16);
}

static __device__ __forceinline__ float bf2f(short s) {
    unsigned u = ((unsigned)(unsigned short)s) << 16;
    return __builtin_bit_cast(float, u);
}

static __device__ __forceinline__ void gld16(const void* g, void* l) {
    __builtin_amdgcn_global_load_lds(
        (const __attribute__((address_space(1))) void*)g,
        (__attribute__((address_space(3))) void*)l, 16, 0, 0);
}

#define VMW_(n) asm volatile("s_waitcnt vmcnt(" #n ")" ::: "memory")
#define VMW(n) VMW_(n)
#define LGKM0() asm volatile("s_waitcnt lgkmcnt(0)" ::: "memory")

// ---------------- routing: padded per-expert lists + row-block table ----------------
__global__ void route_kernel(const int* __restrict__ eidx,
                             const float* __restrict__ aff,
                             int* __restrict__ cnt, int* __restrict__ poff,
                             int* __restrict__ rbE, int* __restrict__ nrbG,
                             int* __restrict__ toks, float* __restrict__ wts,
                             int* __restrict__ inv) {
    __shared__ int scnt[E_];
    __shared__ int spoff[E_];
    __shared__ int scur[E_];
    int tid = threadIdx.x;
    if (tid < E_) scnt[tid] = 0;
    __syncthreads();
    for (int s = tid; s < NSLOT_; s += blockDim.x) {
        atomicAdd(&scnt[eidx[s]], 1);
    }
    __syncthreads();
    if (tid == 0) {
        int acc = 0, rb = 0;
        for (int e = 0; e < E_; ++e) {
            int c = scnt[e];
            cnt[e] = c; poff[e] = acc; spoff[e] = acc;
            int nb = (c + 255) >> 8;
            for (int i = 0; i < nb; ++i) rbE[rb++] = e;
            acc += nb << 8;
        }
        *nrbG = rb;
        for (int i = rb; i < NRBMAX_; ++i) rbE[i] = -1;
    }
    __syncthreads();
    if (tid < E_) scur[tid] = spoff[tid];
    __syncthreads();
    for (int s = tid; s < NSLOT_; s += blockDim.x) {
        int t = s >> 1;
        int e0 = eidx[t * 2], e1 = eidx[t * 2 + 1];
        float a0 = aff[t * E_ + e0], a1 = aff[t * E_ + e1];
        int k = s & 1;
        int e = k ? e1 : e0;
        float w = (k ? a1 : a0) / (a0 + a1);
        int pos = atomicAdd(&scur[e], 1);
        toks[pos] = t;
        wts[pos] = w;
        inv[s] = pos;
    }
    __syncthreads();
    // pads: replicate last real token, weight 0
    for (int e = 0; e < E_; ++e) {
        int c = scnt[e];
        if (c == 0) continue;
        int padded = ((c + 255) >> 8) << 8;
        int lastTok = toks[spoff[e] + c - 1];
        for (int p = c + tid; p < padded; p += blockDim.x) {
            toks[spoff[e] + p] = lastTok;
            wts[spoff[e] + p] = 0.f;
        }
    }
}

// ---------------- gather x -> k-packet bf16 xg[sb][128][4][256][8] ----------------
__global__ __launch_bounds__(256) void gather_x_kernel(const float* __restrict__ x,
                                                       const int* __restrict__ toks,
                                                       const int* __restrict__ nrbG,
                                                       short* __restrict__ xg) {
    int blk = blockIdx.x >> 3;        // 0..39
    if (blk >= *nrbG) return;
    int sc = blockIdx.x & 7;          // slice chunk (16 slices)
    int row = threadIdx.x;            // 0..255
    int g = blk * 256 + row;
    const float* src = x + (size_t)toks[g] * H_ + sc * 512;
    short* dstbase = xg + (size_t)blk * XGBLK_ + (size_t)row * 8;
    for (int s = 0; s < 16; ++s) {
        int slice = sc * 16 + s;
        #pragma unroll
        for (int kg = 0; kg < 4; ++kg) {
            float4 f0 = *(const float4*)(src + s * 32 + kg * 8);
            float4 f1 = *(const float4*)(src + s * 32 + kg * 8 + 4);
            bf16x8 v;
            v[0] = f2bf(f0.x); v[1] = f2bf(f0.y); v[2] = f2bf(f0.z); v[3] = f2bf(f0.w);
            v[4] = f2bf(f1.x); v[5] = f2bf(f1.y); v[6] = f2bf(f1.z); v[7] = f2bf(f1.w);
            *(bf16x8*)(dstbase + (size_t)(slice * 4 + kg) * 2048) = v;
        }
    }
}

// ---------------- coalesced weight repacks (LDS transpose) ----------------
__global__ __launch_bounds__(256) void repack_gu_kernel(const int* __restrict__ wq,
                                                        short* __restrict__ out) {
    __shared__ short sm[64][33];
    int e = blockIdx.z;
    int by = blockIdx.y;              // 0..63
    int bx = blockIdx.x;              // 0..111
    int tid = threadIdx.x;
    {
        int rw = tid >> 2;
        int q = tid & 3;
        int ocol = (q < 2) ? (bx * 16 + q * 8) : (I_ + bx * 16 + (q - 2) * 8);
        const int* src = wq + ((size_t)e * H_ + by * 64 + rw) * TWOI_ + ocol;
        #pragma unroll
        for (int i = 0; i < 8; ++i)
            sm[rw][q * 8 + i] = f2bf((float)(src[i] - 128));
    }
    __syncthreads();
    {
        int yl = tid >> 5;
        int c = tid & 31;
        bf16x8 v;
        #pragma unroll
        for (int i = 0; i < 8; ++i) v[i] = sm[yl * 8 + i][c];
        *(bf16x8*)(out + (((size_t)e * 512 + by * 8 + yl) * TWOI_ + bx * 32 + c) * 8) = v;
    }
}

__global__ __launch_bounds__(256) void repack_dn_kernel(const int* __restrict__ wq,
                                                        short* __restrict__ out) {
    __shared__ short sm[64][33];
    int e = blockIdx.z;
    int by = blockIdx.y;              // 0..27
    int bx = blockIdx.x;              // 0..127
    int tid = threadIdx.x;
    {
        int rw = tid >> 2;
        int q = tid & 3;
        const int* src = wq + ((size_t)e * I_ + by * 64 + rw) * H_ + bx * 32 + q * 8;
        #pragma unroll
        for (int i = 0; i < 8; ++i)
            sm[rw][q * 8 + i] = f2bf((float)(src[i] - 128));
    }
    __syncthreads();
    {
        int yl = tid >> 5;
        int c = tid & 31;
        bf16x8 v;
        #pragma unroll
        for (int i = 0; i < 8; ++i) v[i] = sm[yl * 8 + i][c];
        *(bf16x8*)(out + (((size_t)e * 224 + by * 8 + yl) * H_ + bx * 32 + c) * 8) = v;
    }
}

// ==================== GEMM1 ring-4, template phase order ====================
// phase p: rd(slot p) -> stage(p+2) -> vmcnt(4) -> barA -> lgkm(0) -> MFMA -> barB
__global__ __launch_bounds__(512, 1) void gemm1r_kernel(
    const short* __restrict__ xg,       // k-packet A [sb][...]
    const short* __restrict__ wgu,      // k-packet B (interleaved g/u)
    const float* __restrict__ scale,    // [E,2I]
    const int* __restrict__ rbE, const int* __restrict__ nrbG,
    short* __restrict__ h_pk) {         // k-packet h [sb][...]
    const int xcd = blockIdx.x & 7;
    const int loc = blockIdx.x >> 3;          // 0..69
    const int work = xcd * 70 + loc;          // 0..559
    const int sb = work / 14;                 // 0..39
    const int bx = work % 14;
    if (sb >= *nrbG) return;
    const int e = rbE[sb];

    __shared__ __align__(16) short SM[65536];   // A: [0,32768) B: [32768,65536)

    int tid = threadIdx.x;
    const int lane = tid & 63;
    const int wid = tid >> 6;
    const int wr128 = (wid >> 2) * 128;
    const int wc64 = (wid & 3) * 64;
    const int fr = lane & 15;
    const int kq = lane >> 4;

    const int srow = tid & 255;
    const int kgo2 = (tid >> 8) * 2;    // 0 or 2

    const size_t aoff = (size_t)sb * XGBLK_ + (size_t)srow * 8;
    const size_t bstride = (size_t)TWOI_ * 8;
    const short* bsrc = wgu + (size_t)e * 512 * bstride + (size_t)(bx * 256 + srow) * 8;

    bf16x8 av[8], bv[4];
    f32x4 acc[8][4];
    #pragma unroll
    for (int i = 0; i < 8; ++i)
        #pragma unroll
        for (int jj = 0; jj < 4; ++jj) acc[i][jj] = f32x4{0.f, 0.f, 0.f, 0.f};

#define G1_STG(q, slot) do {                                              \
        _Pragma("unroll")                                                 \
        for (int p_ = 0; p_ < 2; ++p_)                                    \
            gld16(xg + aoff + (size_t)((q) * 4 + kgo2 + p_) * 2048,       \
                  &SM[(((slot) * 4 + kgo2 + p_) * 256 + srow) * 8]);      \
        _Pragma("unroll")                                                 \
        for (int p_ = 0; p_ < 2; ++p_)                                    \
            gld16(bsrc + (size_t)((q) * 4 + kgo2 + p_) * bstride,         \
                  &SM[32768 + (((slot) * 4 + kgo2 + p_) * 256 + srow) * 8]); \
    } while (0)
#define G1_RD(ss) do {                                                    \
        _Pragma("unroll") for (int i_ = 0; i_ < 8; ++i_)                  \
            av[i_] = *(const bf16x8*)&SM[(((ss) * 4 + kq) * 256 + wr128 + i_ * 16 + fr) * 8]; \
        _Pragma("unroll") for (int j_ = 0; j_ < 4; ++j_)                  \
            bv[j_] = *(const bf16x8*)&SM[32768 + (((ss) * 4 + kq) * 256 + wc64 + j_ * 16 + fr) * 8]; \
    } while (0)
#define G1_MM() do {                                                      \
        __builtin_amdgcn_s_setprio(1);                                    \
        _Pragma("unroll") for (int i_ = 0; i_ < 8; ++i_)                  \
        _Pragma("unroll") for (int j_ = 0; j_ < 4; ++j_)                  \
            acc[i_][j_] = __builtin_amdgcn_mfma_f32_16x16x32_bf16(av[i_], bv[j_], acc[i_][j_], 0, 0, 0); \
        __builtin_amdgcn_s_setprio(0);                                    \
    } while (0)
#define G1_PH(ss, q, qs) do {                                             \
        G1_RD(ss);                                                        \
        G1_STG(q, qs);                                                    \
        VMW(4);                                                           \
        __builtin_amdgcn_s_barrier();                                     \
        LGKM0();                                                          \
        __builtin_amdgcn_sched_barrier(0);                                \
        G1_MM();                                                          \
        __builtin_amdgcn_s_barrier();                                     \
    } while (0)
#define G1_PHT(ss) do {                                                   \
        G1_RD(ss);                                                        \
        VMW(0);                                                           \
        __builtin_amdgcn_s_barrier();                                     \
        LGKM0();                                                          \
        __builtin_amdgcn_sched_barrier(0);                                \
        G1_MM();                                                          \
        __builtin_amdgcn_s_barrier();                                     \
    } while (0)
#define G1_PHL(ss) do {                                                   \
        G1_RD(ss);                                                        \
        LGKM0();                                                          \
        __builtin_amdgcn_sched_barrier(0);                                \
        G1_MM();                                                          \
    } while (0)

    // prologue: stage slices 0,1; guarantee slot 0
    G1_STG(0, 0); G1_STG(1, 1);
    VMW(4);
    __builtin_amdgcn_s_barrier();
    // staged phases 0..NS-3 (NS-2 of them); loop covers first NS-6, peel 2
    for (int p = 0; p < NS1_ - 6; p += 4) {
        G1_PH(0, p + 2, 2);
        G1_PH(1, p + 3, 3);
        G1_PH(2, p + 4, 0);
        G1_PH(3, p + 5, 1);
    }
    G1_PH(0, NS1_ - 2, 2);   // phase NS-4
    G1_PH(1, NS1_ - 1, 3);   // phase NS-3
    G1_PHT(2);               // phase NS-2 (drain)
    G1_PHL(3);               // phase NS-1
#undef G1_STG
#undef G1_RD
#undef G1_MM
#undef G1_PH
#undef G1_PHT
#undef G1_PHL

    // ---- epilogue: silu(g)*u -> LDS transpose -> k-packet h_pk (uniform) ----
    __syncthreads();
    const int q4 = lane >> 4;
    #pragma unroll
    for (int cfp = 0; cfp < 2; ++cfp) {
        int ml = (wid & 3) * 2 + cfp;
        int hcol = (bx * 8 + ml) * 16 + fr;
        float gs = scale[e * TWOI_ + hcol];
        float us = scale[e * TWOI_ + I_ + hcol];
        int cl = ml * 16 + fr;
        #pragma unroll
        for (int rf = 0; rf < 8; ++rf) {
            #pragma unroll
            for (int jj = 0; jj < 4; ++jj) {
                int row = wr128 + rf * 16 + q4 * 4 + jj;
                float gv = acc[rf][cfp * 2][jj] * gs;
                float uv = acc[rf][cfp * 2 + 1][jj] * us;
                float s = 1.f / (1.f + __expf(-gv));
                SM[row * 136 + cl] = f2bf(gv * s * uv);
            }
        }
    }
    __syncthreads();
    #pragma unroll
    for (int v = 0; v < 8; ++v) {
        int l = tid & 63;
        int w = tid >> 6;
        int o = w * 2 + (v & 1);
        int rloc = (v >> 1) * 64 + l;
        bf16x8 hv = *(const bf16x8*)&SM[rloc * 136 + o * 8];
        size_t dst = (size_t)sb * HPBLK_
                   + (size_t)((bx * 4 + (o >> 2)) * 4 + (o & 3)) * 2048
                   + (size_t)rloc * 8;
        *(bf16x8*)(h_pk + dst) = hv;
    }
}

// ==================== GEMM2 ring-4, template phase order ====================
__global__ __launch_bounds__(512, 1) void gemm2s_kernel(
    const short* __restrict__ h_pk,     // k-packet A [sb][...]
    const short* __restrict__ wd,       // k-packet B
    const float* __restrict__ dscale,   // [E,H]
    const int* __restrict__ rbE, const int* __restrict__ nrbG,
    const float* __restrict__ wts,
    short* __restrict__ dscr) {         // [padded slots, H] bf16
    const int xcd = blockIdx.x & 7;
    const int loc = blockIdx.x >> 3;          // 0..79
    const int work = xcd * 80 + loc;          // 0..639
    const int sb = work / 16;                 // 0..39
    const int bx = work % 16;
    if (sb >= *nrbG) return;
    const int e = rbE[sb];

    __shared__ __align__(16) short SM[65536];
    __shared__ float swt[256];

    int tid = threadIdx.x;
    if (tid < 256) swt[tid] = wts[sb * 256 + tid];
    __syncthreads();

    const int lane = tid & 63;
    const int wid = tid >> 6;
    const int wr128 = (wid >> 2) * 128;
    const int wc64 = (wid & 3) * 64;
    const int fr = lane & 15;
    const int kq = lane >> 4;

    const int srow = tid & 255;
    const int kgo2 = (tid >> 8) * 2;

    const size_t aoff = (size_t)sb * HPBLK_ + (size_t)srow * 8;
    const size_t bstride = (size_t)H_ * 8;
    const short* bsrc = wd + (size_t)e * 224 * bstride + (size_t)(bx * 256 + srow) * 8;

    bf16x8 av[8], bv[4];
    f32x4 acc[8][4];
    #pragma unroll
    for (int i = 0; i < 8; ++i)
        #pragma unroll
        for (int jj = 0; jj < 4; ++jj) acc[i][jj] = f32x4{0.f, 0.f, 0.f, 0.f};

#define G2_STG(q, slot) do {                                              \
        _Pragma("unroll")                                                 \
        for (int p_ = 0; p_ < 2; ++p_)                                    \
            gld16(h_pk + aoff + (size_t)((q) * 4 + kgo2 + p_) * 2048,     \
                  &SM[(((slot) * 4 + kgo2 + p_) * 256 + srow) * 8]);      \
        _Pragma("unroll")                                                 \
        for (int p_ = 0; p_ < 2; ++p_)                                    \
            gld16(bsrc + (size_t)((q) * 4 + kgo2 + p_) * bstride,         \
                  &SM[32768 + (((slot) * 4 + kgo2 + p_) * 256 + srow) * 8]); \
    } while (0)
#define G2_RD(ss) do {                                                    \
        _Pragma("unroll") for (int i_ = 0; i_ < 8; ++i_)                  \
            av[i_] = *(const bf16x8*)&SM[(((ss) * 4 + kq) * 256 + wr128 + i_ * 16 + fr) * 8]; \
        _Pragma("unroll") for (int j_ = 0; j_ < 4; ++j_)                  \
            bv[j_] = *(const bf16x8*)&SM[32768 + (((ss) * 4 + kq) * 256 + wc64 + j_ * 16 + fr) * 8]; \
    } while (0)
#define G2_MM() do {                                                      \
        __builtin_amdgcn_s_setprio(1);                                    \
        _Pragma("unroll") for (int i_ = 0; i_ < 8; ++i_)                  \
        _Pragma("unroll") for (int j_ = 0; j_ < 4; ++j_)                  \
            acc[i_][j_] = __builtin_amdgcn_mfma_f32_16x16x32_bf16(av[i_], bv[j_], acc[i_][j_], 0, 0, 0); \
        __builtin_amdgcn_s_setprio(0);                                    \
    } while (0)
#define G2_PH(ss, q, qs) do {                                             \
        G2_RD(ss);                                                        \
        G2_STG(q, qs);                                                    \
        VMW(4);                                                           \
        __builtin_amdgcn_s_barrier();                                     \
        LGKM0();                                                          \
        __builtin_amdgcn_sched_barrier(0);                                \
        G2_MM();                                                          \
        __builtin_amdgcn_s_barrier();                                     \
    } while (0)
#define G2_PHT(ss) do {                                                   \
        G2_RD(ss);                                                        \
        VMW(0);                                                           \
        __builtin_amdgcn_s_barrier();                                     \
        LGKM0();                                                          \
        __builtin_amdgcn_sched_barrier(0);                                \
        G2_MM();                                                          \
        __builtin_amdgcn_s_barrier();                                     \
    } while (0)
#define G2_PHL(ss) do {                                                   \
        G2_RD(ss);                                                        \
        LGKM0();                                                          \
        __builtin_amdgcn_sched_barrier(0);                                \
        G2_MM();                                                          \
    } while (0)

    G2_STG(0, 0); G2_STG(1, 1);
    VMW(4);
    __builtin_amdgcn_s_barrier();
    for (int p = 0; p < NS2_ - 6; p += 4) {
        G2_PH(0, p + 2, 2);
        G2_PH(1, p + 3, 3);
        G2_PH(2, p + 4, 0);
        G2_PH(3, p + 5, 1);
    }
    G2_PH(0, NS2_ - 2, 2);
    G2_PH(1, NS2_ - 1, 3);
    G2_PHT(2);
    G2_PHL(3);
#undef G2_STG
#undef G2_RD
#undef G2_MM
#undef G2_PH
#undef G2_PHT
#undef G2_PHL

    // ---- epilogue: scale -> LDS transpose -> coalesced bf16x8 store (uniform) ----
    __syncthreads();
    const int q4 = lane >> 4;
    const int wn = wid & 3;
    #pragma unroll
    for (int pass = 0; pass < 2; ++pass) {
        if ((wn >> 1) == pass) {
            #pragma unroll
            for (int cf = 0; cf < 4; ++cf) {
                int colL = (wn & 1) * 64 + cf * 16 + fr;       // 0..127
                int col = bx * 256 + pass * 128 + colL;
                float ds = dscale[e * H_ + col];
                #pragma unroll
                for (int rf = 0; rf < 8; ++rf) {
                    #pragma unroll
                    for (int jj = 0; jj < 4; ++jj) {
                        int row = wr128 + rf * 16 + q4 * 4 + jj;
                        SM[row * 136 + colL] = f2bf(acc[rf][cf][jj] * ds * swt[row]);
                    }
                }
            }
        }
        __syncthreads();
        #pragma unroll
        for (int v = 0; v < 8; ++v) {
            int l = tid & 63;
            int w8 = tid >> 6;
            int o = w8 * 2 + (v & 1);          // 0..15
            int rloc = (v >> 1) * 64 + l;      // 0..255
            bf16x8 hv = *(const bf16x8*)&SM[rloc * 136 + o * 8];
            *(bf16x8*)(dscr + (size_t)(sb * 256 + rloc) * H_
                       + bx * 256 + pass * 128 + o * 8) = hv;
        }
        __syncthreads();
    }
}

// ---------------- combine: out[t] = dscr[inv[2t]] + dscr[inv[2t+1]] ----------------
__global__ __launch_bounds__(256) void combine_kernel(
    const short* __restrict__ dscr, const int* __restrict__ inv,
    float* __restrict__ out) {
    int idx = blockIdx.x * 256 + threadIdx.x;   // 0 .. T*H/8-1
    int t = idx >> 9;                           // H/8 = 512 chunks per token
    int c8 = (idx & 511) * 8;
    int s0 = inv[t * 2], s1 = inv[t * 2 + 1];
    bf16x8 a = *(const bf16x8*)(dscr + (size_t)s0 * H_ + c8);
    bf16x8 b = *(const bf16x8*)(dscr + (size_t)s1 * H_ + c8);
    float4 o0, o1;
    o0.x = bf2f(a[0]) + bf2f(b[0]);
    o0.y = bf2f(a[1]) + bf2f(b[1]);
    o0.z = bf2f(a[2]) + bf2f(b[2]);
    o0.w = bf2f(a[3]) + bf2f(b[3]);
    o1.x = bf2f(a[4]) + bf2f(b[4]);
    o1.y = bf2f(a[5]) + bf2f(b[5]);
    o1.z = bf2f(a[6]) + bf2f(b[6]);
    o1.w = bf2f(a[7]) + bf2f(b[7]);
    *(float4*)(out + (size_t)t * H_ + c8) = o0;
    *(float4*)(out + (size_t)t * H_ + c8 + 4) = o1;
}

// ================= fallback path (fused int32 dequant, known-good) =================
__global__ __launch_bounds__(256) void gemm1_kernel(
    const float* __restrict__ x, const int* __restrict__ wq,
    const float* __restrict__ scale,
    const int* __restrict__ cnt, const int* __restrict__ off,
    const int* __restrict__ toks, short* __restrict__ h_ws) {
    int e = blockIdx.z;
    int cn = cnt[e];
    int row0 = blockIdx.y * 128;
    if (row0 >= cn) return;
    int base = off[e];
    int c0 = blockIdx.x * 64;
    __shared__ __align__(16) short As[4][128][8];
    __shared__ __align__(16) short Bg[4][64][8];
    __shared__ __align__(16) short Bu[4][64][8];
    __shared__ int stok[128];
    int tid = threadIdx.x;
    if (tid < 128) {
        int r = row0 + tid;
        stok[tid] = toks[base + (r < cn ? r : 0)];
    }
    __syncthreads();
    const int lane = tid & 63;
    const int wid = tid >> 6;
    const int wrow = (wid >> 1) * 64;
    const int wcc = (wid & 1) * 32;
    const int fr = lane & 15;
    const int kg = lane >> 4;
    f32x4 accg[4][2], accu[4][2];
    #pragma unroll
    for (int i = 0; i < 4; ++i)
        #pragma unroll
        for (int j = 0; j < 2; ++j) {
            accg[i][j] = f32x4{0.f, 0.f, 0.f, 0.f};
            accu[i][j] = f32x4{0.f, 0.f, 0.f, 0.f};
        }
    const int ar = tid & 127;
    const int akg = (tid >> 7) * 2;
    const int bc = tid & 63;
    const int bkg = (tid >> 6) & 3;
    const float* xrow = x + (size_t)stok[ar] * H_;
    const int* wg = wq + (size_t)e * H_ * TWOI_ + c0 + bc;
    const int* wu = wg + I_;
    for (int kk = 0; kk < H_; kk += 32) {
        {
            const float* xp = xrow + kk + akg * 8;
            #pragma unroll
            for (int p = 0; p < 2; ++p) {
                float4 f0 = *(const float4*)(xp + p * 8);
                float4 f1 = *(const float4*)(xp + p * 8 + 4);
                bf16x8 v;
                v[0] = f2bf(f0.x); v[1] = f2bf(f0.y); v[2] = f2bf(f0.z); v[3] = f2bf(f0.w);
                v[4] = f2bf(f1.x); v[5] = f2bf(f1.y); v[6] = f2bf(f1.z); v[7] = f2bf(f1.w);
                *(bf16x8*)&As[akg + p][ar][0] = v;
            }
        }
        {
            const int* wpg = wg + (size_t)(kk + bkg * 8) * TWOI_;
            const int* wpu = wu + (size_t)(kk + bkg * 8) * TWOI_;
            bf16x8 vg, vu;
            #pragma unroll
            for (int j = 0; j < 8; ++j) {
                vg[j] = f2bf((float)wpg[(size_t)j * TWOI_] - 128.f);
                vu[j] = f2bf((float)wpu[(size_t)j * TWOI_] - 128.f);
            }
            *(bf16x8*)&Bg[bkg][bc][0] = vg;
            *(bf16x8*)&Bu[bkg][bc][0] = vu;
        }
        __syncthreads();
        bf16x8 a[4], bg[2], bu[2];
        #pragma unroll
        for (int rf = 0; rf < 4; ++rf) a[rf] = *(const bf16x8*)&As[kg][wrow + rf * 16 + fr][0];
        #pragma unroll
        for (int cf = 0; cf < 2; ++cf) {
            bg[cf] = *(const bf16x8*)&Bg[kg][wcc + cf * 16 + fr][0];
            bu[cf] = *(const bf16x8*)&Bu[kg][wcc + cf * 16 + fr][0];
        }
        #pragma unroll
        for (int rf = 0; rf < 4; ++rf)
            #pragma unroll
            for (int cf = 0; cf < 2; ++cf) {
                accg[rf][cf] = __builtin_amdgcn_mfma_f32_16x16x32_bf16(a[rf], bg[cf], accg[rf][cf], 0, 0, 0);
                accu[rf][cf] = __builtin_amdgcn_mfma_f32_16x16x32_bf16(a[rf], bu[cf], accu[rf][cf], 0, 0, 0);
            }
        __syncthreads();
    }
    const int q4 = lane >> 4;
    #pragma unroll
    for (int cf = 0; cf < 2; ++cf) {
        int col = c0 + wcc + cf * 16 + fr;
        float gs = scale[e * TWOI_ + col];
        float us = scale[e * TWOI_ + I_ + col];
        #pragma unroll
        for (int rf = 0; rf < 4; ++rf) {
            #pragma unroll
            for (int j = 0; j < 4; ++j) {
                int row = wrow + rf * 16 + q4 * 4 + j;
                if (row0 + row < cn) {
                    float gv = accg[rf][cf][j] * gs;
                    float uv = accu[rf][cf][j] * us;
                    float s = 1.f / (1.f + __expf(-gv));
                    h_ws[(size_t)(base + row0 + row) * I_ + col] = f2bf(gv * s * uv);
                }
            }
        }
    }
}

__global__ __launch_bounds__(256) void gemm2_kernel(
    const short* __restrict__ h_ws, const int* __restrict__ wq,
    const float* __restrict__ dscale,
    const int* __restrict__ cnt, const int* __restrict__ off,
    const int* __restrict__ toks, const float* __restrict__ wts,
    float* __restrict__ out) {
    int e = blockIdx.z;
    int cn = cnt[e];
    int row0 = blockIdx.y * 128;
    if (row0 >= cn) return;
    int base = off[e];
    int c0 = blockIdx.x * 128;
    __shared__ __align__(16) short As[4][128][8];
    __shared__ __align__(16) short Bs[4][128][8];
    __shared__ int stok[128];
    __shared__ float swt[128];
    int tid = threadIdx.x;
    if (tid < 128) {
        int r = row0 + tid;
        int idx = base + (r < cn ? r : 0);
        stok[tid] = toks[idx];
        swt[tid] = (r < cn) ? wts[idx] : 0.f;
    }
    __syncthreads();
    const int lane = tid & 63;
    const int wid = tid >> 6;
    const int wrow = (wid >> 1) * 64;
    const int wcc = (wid & 1) * 64;
    const int fr = lane & 15;
    const int kg = lane >> 4;
    f32x4 acc[4][4];
    #pragma unroll
    for (int i = 0; i < 4; ++i)
        #pragma unroll
        for (int j = 0; j < 4; ++j) acc[i][j] = f32x4{0.f, 0.f, 0.f, 0.f};
    const int ar = tid & 127;
    const int akg = (tid >> 7) * 2;
    const int bc = tid & 127;
    const int bkg2 = (tid >> 7) * 2;
    const short* hrow = h_ws + (size_t)(base + ((row0 + ar) < cn ? row0 + ar : 0)) * I_;
    const int* wcol = wq + (size_t)e * I_ * H_ + c0 + bc;
    for (int kk = 0; kk < I_; kk += 32) {
        #pragma unroll
        for (int p = 0; p < 2; ++p) {
            *(bf16x8*)&As[akg + p][ar][0] = *(const bf16x8*)(hrow + kk + (akg + p) * 8);
        }
        #pragma unroll
        for (int p = 0; p < 2; ++p) {
            const int* wp = wcol + (size_t)(kk + (bkg2 + p) * 8) * H_;
            bf16x8 v;
            #pragma unroll
            for (int j = 0; j < 8; ++j) v[j] = f2bf((float)wp[(size_t)j * H_] - 128.f);
            *(bf16x8*)&Bs[bkg2 + p][bc][0] = v;
        }
        __syncthreads();
        bf16x8 a[4], b[4];
        #pragma unroll
        for (int rf = 0; rf < 4; ++rf) a[rf] = *(const bf16x8*)&As[kg][wrow + rf * 16 + fr][0];
        #pragma unroll
        for (int cf = 0; cf < 4; ++cf) b[cf] = *(const bf16x8*)&Bs[kg][wcc + cf * 16 + fr][0];
        #pragma unroll
        for (int rf = 0; rf < 4; ++rf)
            #pragma unroll
            for (int cf = 0; cf < 4; ++cf)
                acc[rf][cf] = __builtin_amdgcn_mfma_f32_16x16x32_bf16(a[rf], b[cf], acc[rf][cf], 0, 0, 0);
        __syncthreads();
    }
    const int q4 = lane >> 4;
    #pragma unroll
    for (int cf = 0; cf < 4; ++cf) {
        int col = c0 + wcc + cf * 16 + fr;
        float ds = dscale[e * H_ + col];
        #pragma unroll
        for (int rf = 0; rf < 4; ++rf) {
            #pragma unroll
            for (int j = 0; j < 4; ++j) {
                int row = wrow + rf * 16 + q4 * 4 + j;
                if (row0 + row < cn) {
                    float v = acc[rf][cf][j] * ds * swt[row];
                    atomicAdd(&out[(size_t)stok[row] * H_ + col], v);
                }
            }
        }
    }
}

extern "C" void kernel_launch(void* const* d_in, const int* in_sizes, int n_in,
                              void* d_out, int out_size, void* d_ws, size_t ws_size,
                              hipStream_t stream) {
    const float* x     = (const float*)d_in[0];
    const float* aff   = (const float*)d_in[1];
    const int*   guq   = (const int*)d_in[2];
    const float* gus   = (const float*)d_in[3];
    const int*   dwq   = (const int*)d_in[4];
    const float* dsc   = (const float*)d_in[5];
    const int*   eidx  = (const int*)d_in[6];
    float* out = (float*)d_out;

    char* ws = (char*)d_ws;
    int*   cnt  = (int*)ws;                      // 8
    int*   poff = cnt + 8;                       // 8
    int*   nrbG = cnt + 16;                      // 1
    int*   rbE  = cnt + 32;                      // 64
    int*   toks = (int*)(ws + 1024);             // 10240
    float* wts  = (float*)(ws + 1024 + NRBMAX_ * 256 * 4);
    int*   inv  = (int*)(ws + 1024 + NRBMAX_ * 256 * 8);   // 8192

    const size_t off_h  = (size_t)1 << 20;
    const size_t sz_h   = (size_t)NRBMAX_ * HPBLK_ * 2;     // 36.7 MB
    const size_t off_xg = off_h + sz_h;
    const size_t sz_xg  = (size_t)NRBMAX_ * XGBLK_ * 2;     // 83.9 MB (xg, reused as dscr)
    const size_t off_gu = off_xg + sz_xg;
    const size_t sz_gu  = (size_t)E_ * 512 * TWOI_ * 8 * 2; // 234.9 MB
    const size_t off_dn = off_gu + sz_gu;
    const size_t sz_dn  = (size_t)E_ * 224 * H_ * 8 * 2;    // 117.4 MB
    const size_t NEED   = off_dn + sz_dn;                   // ~474 MB

    short* h_pk = (short*)(ws + off_h);

    route_kernel<<<1, 1024, 0, stream>>>(eidx, aff, cnt, poff, rbE, nrbG, toks, wts, inv);

    if (ws_size >= NEED) {
        short* xg   = (short*)(ws + off_xg);    // also dscr after gemm1r
        short* wgur = (short*)(ws + off_gu);
        short* wdr  = (short*)(ws + off_dn);

        gather_x_kernel<<<NRBMAX_ * 8, 256, 0, stream>>>(x, toks, nrbG, xg);
        dim3 rg1(TWOI_ / 32, H_ / 64, E_);
        repack_gu_kernel<<<rg1, 256, 0, stream>>>(guq, wgur);
        dim3 rg2(H_ / 32, I_ / 64, E_);
        repack_dn_kernel<<<rg2, 256, 0, stream>>>(dwq, wdr);

        gemm1r_kernel<<<14 * NRBMAX_, 512, 0, stream>>>(xg, wgur, gus, rbE, nrbG, h_pk);
        // xg dead; reuse as dscr
        gemm2s_kernel<<<16 * NRBMAX_, 512, 0, stream>>>(h_pk, wdr, dsc, rbE, nrbG, wts, xg);
        combine_kernel<<<(T_ * H_ / 8) / 256, 256, 0, stream>>>(xg, inv, out);
    } else {
        hipMemsetAsync(d_out, 0, (size_t)out_size * sizeof(float), stream);
        dim3 g1(I_ / 64, NSLOT_ / 128, E_);
        gemm1_kernel<<<g1, 256, 0, stream>>>(x, guq, gus, cnt, poff, toks, h_pk);
        dim3 g2(H_ / 128, NSLOT_ / 128, E_);
        gemm2_kernel<<<g2, 256, 0, stream>>>(h_pk, dwq, dsc, cnt, poff, toks, wts, out);
    }
}

// Round 12
// 830.936 us; speedup vs baseline: 1.0376x; 1.0376x over previous
//
#include <hip/hip_runtime.h>
#include <hip/hip_bf16.h>
#include <stdint.h>

#define E_ 8
#define H_ 4096
#define I_ 1792
#define TWOI_ 3584
#define T_ 4096
#define NSLOT_ 8192
#define NRBMAX_ 40        /* max padded 256-slot blocks */
#define XGBLK_ 1048576    /* shorts per xg slot-block: 512*256*8 */
#define HPBLK_ 458752     /* shorts per h_pk slot-block: 224*256*8 */

typedef __attribute__((ext_vector_type(4))) float f32x4;
typedef __attribute__((ext_vector_type(8))) short bf16x8;

static __device__ __forceinline__ short f2bf(float f) {
    unsigned u = __builtin_bit_cast(unsigned, f);
    u += 0x7FFF + ((u >> 16) & 1);   // round-to-nearest-even
    return (short)(u >> 16);
}

static __device__ __forceinline__ float bf2f(short s) {
    unsigned u = ((unsigned)(unsigned short)s) << 16;
    return __builtin_bit_cast(float, u);
}

static __device__ __forceinline__ void gld16(const void* g, void* l) {
    __builtin_amdgcn_global_load_lds(
        (const __attribute__((address_space(1))) void*)g,
        (__attribute__((address_space(3))) void*)l, 16, 0, 0);
}

// ---------------- routing: padded per-expert lists + row-block table ----------------
__global__ void route_kernel(const int* __restrict__ eidx,
                             const float* __restrict__ aff,
                             int* __restrict__ cnt, int* __restrict__ poff,
                             int* __restrict__ rbE, int* __restrict__ nrbG,
                             int* __restrict__ toks, float* __restrict__ wts,
                             int* __restrict__ inv) {
    __shared__ int scnt[E_];
    __shared__ int spoff[E_];
    __shared__ int scur[E_];
    int tid = threadIdx.x;
    if (tid < E_) scnt[tid] = 0;
    __syncthreads();
    for (int s = tid; s < NSLOT_; s += blockDim.x) {
        atomicAdd(&scnt[eidx[s]], 1);
    }
    __syncthreads();
    if (tid == 0) {
        int acc = 0, rb = 0;
        for (int e = 0; e < E_; ++e) {
            int c = scnt[e];
            cnt[e] = c; poff[e] = acc; spoff[e] = acc;
            int nb = (c + 255) >> 8;
            for (int i = 0; i < nb; ++i) rbE[rb++] = e;
            acc += nb << 8;
        }
        *nrbG = rb;
        for (int i = rb; i < NRBMAX_; ++i) rbE[i] = -1;
    }
    __syncthreads();
    if (tid < E_) scur[tid] = spoff[tid];
    __syncthreads();
    for (int s = tid; s < NSLOT_; s += blockDim.x) {
        int t = s >> 1;
        int e0 = eidx[t * 2], e1 = eidx[t * 2 + 1];
        float a0 = aff[t * E_ + e0], a1 = aff[t * E_ + e1];
        int k = s & 1;
        int e = k ? e1 : e0;
        float w = (k ? a1 : a0) / (a0 + a1);
        int pos = atomicAdd(&scur[e], 1);
        toks[pos] = t;
        wts[pos] = w;
        inv[s] = pos;
    }
    __syncthreads();
    // pads: replicate last real token, weight 0
    for (int e = 0; e < E_; ++e) {
        int c = scnt[e];
        if (c == 0) continue;
        int padded = ((c + 255) >> 8) << 8;
        int lastTok = toks[spoff[e] + c - 1];
        for (int p = c + tid; p < padded; p += blockDim.x) {
            toks[spoff[e] + p] = lastTok;
            wts[spoff[e] + p] = 0.f;
        }
    }
}

// ---------------- gather x -> k-packet bf16 xg[sb][512 kp][256 row][8] ----------------
__global__ __launch_bounds__(256) void gather_x_kernel(const float* __restrict__ x,
                                                       const int* __restrict__ toks,
                                                       const int* __restrict__ nrbG,
                                                       short* __restrict__ xg) {
    int blk = blockIdx.x >> 3;        // 0..39
    if (blk >= *nrbG) return;
    int sc = blockIdx.x & 7;          // 64-kp chunk
    int row = threadIdx.x;            // 0..255
    int g = blk * 256 + row;
    const float* src = x + (size_t)toks[g] * H_ + sc * 512;
    short* dstbase = xg + (size_t)blk * XGBLK_ + (size_t)row * 8;
    for (int s = 0; s < 16; ++s) {
        #pragma unroll
        for (int kg = 0; kg < 4; ++kg) {
            float4 f0 = *(const float4*)(src + s * 32 + kg * 8);
            float4 f1 = *(const float4*)(src + s * 32 + kg * 8 + 4);
            bf16x8 v;
            v[0] = f2bf(f0.x); v[1] = f2bf(f0.y); v[2] = f2bf(f0.z); v[3] = f2bf(f0.w);
            v[4] = f2bf(f1.x); v[5] = f2bf(f1.y); v[6] = f2bf(f1.z); v[7] = f2bf(f1.w);
            *(bf16x8*)(dstbase + (size_t)((sc * 16 + s) * 4 + kg) * 2048) = v;
        }
    }
}

// ---------------- coalesced weight repacks (LDS transpose) ----------------
__global__ __launch_bounds__(256) void repack_gu_kernel(const int* __restrict__ wq,
                                                        short* __restrict__ out) {
    __shared__ short sm[64][33];
    int e = blockIdx.z;
    int by = blockIdx.y;              // 0..63
    int bx = blockIdx.x;              // 0..111
    int tid = threadIdx.x;
    {
        int rw = tid >> 2;
        int q = tid & 3;
        int ocol = (q < 2) ? (bx * 16 + q * 8) : (I_ + bx * 16 + (q - 2) * 8);
        const int* src = wq + ((size_t)e * H_ + by * 64 + rw) * TWOI_ + ocol;
        #pragma unroll
        for (int i = 0; i < 8; ++i)
            sm[rw][q * 8 + i] = f2bf((float)(src[i] - 128));
    }
    __syncthreads();
    {
        int yl = tid >> 5;
        int c = tid & 31;
        bf16x8 v;
        #pragma unroll
        for (int i = 0; i < 8; ++i) v[i] = sm[yl * 8 + i][c];
        *(bf16x8*)(out + (((size_t)e * 512 + by * 8 + yl) * TWOI_ + bx * 32 + c) * 8) = v;
    }
}

__global__ __launch_bounds__(256) void repack_dn_kernel(const int* __restrict__ wq,
                                                        short* __restrict__ out) {
    __shared__ short sm[64][33];
    int e = blockIdx.z;
    int by = blockIdx.y;              // 0..27
    int bx = blockIdx.x;              // 0..127
    int tid = threadIdx.x;
    {
        int rw = tid >> 2;
        int q = tid & 3;
        const int* src = wq + ((size_t)e * I_ + by * 64 + rw) * H_ + bx * 32 + q * 8;
        #pragma unroll
        for (int i = 0; i < 8; ++i)
            sm[rw][q * 8 + i] = f2bf((float)(src[i] - 128));
    }
    __syncthreads();
    {
        int yl = tid >> 5;
        int c = tid & 31;
        bf16x8 v;
        #pragma unroll
        for (int i = 0; i < 8; ++i) v[i] = sm[yl * 8 + i][c];
        *(bf16x8*)(out + (((size_t)e * 224 + by * 8 + yl) * H_ + bx * 32 + c) * 8) = v;
    }
}

// ==================== GEMM1 m97-style: BM=128 BN=256 BK=64, 48KB LDS, 2 blk/CU ====================
__global__ __launch_bounds__(512, 4) void gemm1m_kernel(
    const short* __restrict__ xg,       // k-packet A [sb][512][256][8]
    const short* __restrict__ wgu,      // k-packet B [e][512][3584][8] (g/u interleaved)
    const float* __restrict__ scale,    // [E,2I]
    const int* __restrict__ rbE, const int* __restrict__ nrbG,
    short* __restrict__ h_pk) {         // k-packet h [sb][224][256][8]
    const int xcd = blockIdx.x & 7;
    const int loc = blockIdx.x >> 3;          // 0..139
    const int work = xcd * 140 + loc;         // 0..1119
    const int bx = work / 80;                 // 0..13
    const int by = work % 80;                 // 0..79 (128-row blocks)
    const int sb = by >> 1;
    if (sb >= *nrbG) return;
    const int e = rbE[sb];
    const int half = by & 1;

    __shared__ __align__(16) short SM[24576];   // A:[0,8192) B:[8192,24576)

    int tid = threadIdx.x;
    const int lane = tid & 63;
    const int wid = tid >> 6;
    const int wr64 = (wid >> 2) * 64;
    const int wc64 = (wid & 3) * 64;
    const int fr = lane & 15;
    const int kq = lane >> 4;

    const int arow = tid & 127;
    const int akg = tid >> 7;                  // 0..3 (+4 for 2nd load)
    const int bcol = tid & 255;
    const int bkg = tid >> 8;                  // 0..1 (kgrp = bkg*4+p)

    const size_t asrc0 = (size_t)sb * XGBLK_ + (size_t)(half * 128 + arow) * 8;
    const size_t bstr = (size_t)TWOI_ * 8;
    const short* bbase = wgu + (size_t)e * 512 * bstr + (size_t)(bx * 256 + bcol) * 8;

    f32x4 acc[4][4];
    #pragma unroll
    for (int i = 0; i < 4; ++i)
        #pragma unroll
        for (int j = 0; j < 4; ++j) acc[i][j] = f32x4{0.f, 0.f, 0.f, 0.f};

    for (int st = 0; st < 64; ++st) {
        #pragma unroll
        for (int p = 0; p < 2; ++p) {
            const int kg = akg + p * 4;
            gld16(xg + asrc0 + (size_t)(st * 8 + kg) * 2048, &SM[(kg * 128 + arow) * 8]);
        }
        #pragma unroll
        for (int p = 0; p < 4; ++p) {
            const int kg = bkg * 4 + p;
            gld16(bbase + (size_t)(st * 8 + kg) * bstr, &SM[8192 + (kg * 256 + bcol) * 8]);
        }
        __syncthreads();
        #pragma unroll
        for (int s = 0; s < 2; ++s) {
            const int kgq = s * 4 + kq;
            bf16x8 av[4], bv[4];
            #pragma unroll
            for (int i = 0; i < 4; ++i)
                av[i] = *(const bf16x8*)&SM[(kgq * 128 + wr64 + i * 16 + fr) * 8];
            #pragma unroll
            for (int j = 0; j < 4; ++j)
                bv[j] = *(const bf16x8*)&SM[8192 + (kgq * 256 + wc64 + j * 16 + fr) * 8];
            #pragma unroll
            for (int i = 0; i < 4; ++i)
                #pragma unroll
                for (int j = 0; j < 4; ++j)
                    acc[i][j] = __builtin_amdgcn_mfma_f32_16x16x32_bf16(av[i], bv[j], acc[i][j], 0, 0, 0);
        }
        __syncthreads();
    }

    // ---- epilogue: silu(g)*u -> LDS transpose (128x136) -> k-packet h_pk ----
    const int q4 = lane >> 4;
    #pragma unroll
    for (int cfp = 0; cfp < 2; ++cfp) {
        int ml = (wid & 3) * 2 + cfp;          // local 16-col h block 0..7
        int hcol = (bx * 8 + ml) * 16 + fr;
        float gs = scale[e * TWOI_ + hcol];
        float us = scale[e * TWOI_ + I_ + hcol];
        int cl = ml * 16 + fr;                 // 0..127
        #pragma unroll
        for (int i = 0; i < 4; ++i) {
            #pragma unroll
            for (int jj = 0; jj < 4; ++jj) {
                int row = wr64 + i * 16 + q4 * 4 + jj;
                float gv = acc[i][cfp * 2][jj] * gs;
                float uv = acc[i][cfp * 2 + 1][jj] * us;
                float s = 1.f / (1.f + __expf(-gv));
                SM[row * 136 + cl] = f2bf(gv * s * uv);
            }
        }
    }
    __syncthreads();
    #pragma unroll
    for (int v = 0; v < 4; ++v) {
        int rloc = tid & 127;
        int o = v * 4 + (tid >> 7);            // 0..15
        bf16x8 hv = *(const bf16x8*)&SM[rloc * 136 + o * 8];
        *(bf16x8*)(h_pk + (size_t)sb * HPBLK_
                   + (size_t)(bx * 16 + o) * 2048
                   + (size_t)(half * 128 + rloc) * 8) = hv;
    }
}

// ==================== GEMM2 m97-style: BM=128 BN=256 BK=64 ====================
__global__ __launch_bounds__(512, 4) void gemm2m_kernel(
    const short* __restrict__ h_pk,     // k-packet A [sb][224][256][8]
    const short* __restrict__ wd,       // k-packet B [e][224][4096][8]
    const float* __restrict__ dscale,   // [E,H]
    const int* __restrict__ rbE, const int* __restrict__ nrbG,
    const float* __restrict__ wts,
    short* __restrict__ dscr) {         // [padded slots, H] bf16
    const int xcd = blockIdx.x & 7;
    const int loc = blockIdx.x >> 3;          // 0..159
    const int work = xcd * 160 + loc;         // 0..1279
    const int bx = work / 80;                 // 0..15
    const int by = work % 80;
    const int sb = by >> 1;
    if (sb >= *nrbG) return;
    const int e = rbE[sb];
    const int half = by & 1;

    __shared__ __align__(16) short SM[24576];
    __shared__ float swt[128];

    int tid = threadIdx.x;
    if (tid < 128) swt[tid] = wts[sb * 256 + half * 128 + tid];
    __syncthreads();

    const int lane = tid & 63;
    const int wid = tid >> 6;
    const int wr64 = (wid >> 2) * 64;
    const int wc64 = (wid & 3) * 64;
    const int fr = lane & 15;
    const int kq = lane >> 4;

    const int arow = tid & 127;
    const int akg = tid >> 7;
    const int bcol = tid & 255;
    const int bkg = tid >> 8;

    const size_t asrc0 = (size_t)sb * HPBLK_ + (size_t)(half * 128 + arow) * 8;
    const size_t bstr = (size_t)H_ * 8;
    const short* bbase = wd + (size_t)e * 224 * bstr + (size_t)(bx * 256 + bcol) * 8;

    f32x4 acc[4][4];
    #pragma unroll
    for (int i = 0; i < 4; ++i)
        #pragma unroll
        for (int j = 0; j < 4; ++j) acc[i][j] = f32x4{0.f, 0.f, 0.f, 0.f};

    for (int st = 0; st < 28; ++st) {
        #pragma unroll
        for (int p = 0; p < 2; ++p) {
            const int kg = akg + p * 4;
            gld16(h_pk + asrc0 + (size_t)(st * 8 + kg) * 2048, &SM[(kg * 128 + arow) * 8]);
        }
        #pragma unroll
        for (int p = 0; p < 4; ++p) {
            const int kg = bkg * 4 + p;
            gld16(bbase + (size_t)(st * 8 + kg) * bstr, &SM[8192 + (kg * 256 + bcol) * 8]);
        }
        __syncthreads();
        #pragma unroll
        for (int s = 0; s < 2; ++s) {
            const int kgq = s * 4 + kq;
            bf16x8 av[4], bv[4];
            #pragma unroll
            for (int i = 0; i < 4; ++i)
                av[i] = *(const bf16x8*)&SM[(kgq * 128 + wr64 + i * 16 + fr) * 8];
            #pragma unroll
            for (int j = 0; j < 4; ++j)
                bv[j] = *(const bf16x8*)&SM[8192 + (kgq * 256 + wc64 + j * 16 + fr) * 8];
            #pragma unroll
            for (int i = 0; i < 4; ++i)
                #pragma unroll
                for (int j = 0; j < 4; ++j)
                    acc[i][j] = __builtin_amdgcn_mfma_f32_16x16x32_bf16(av[i], bv[j], acc[i][j], 0, 0, 0);
        }
        __syncthreads();
    }

    // ---- epilogue: scale*combine -> LDS transpose (two 128-col passes) -> dscr ----
    const int q4 = lane >> 4;
    const int wn = wid & 3;
    #pragma unroll
    for (int pass = 0; pass < 2; ++pass) {
        if ((wn >> 1) == pass) {
            #pragma unroll
            for (int j = 0; j < 4; ++j) {
                int colL = (wn & 1) * 64 + j * 16 + fr;        // 0..127
                int col = bx * 256 + pass * 128 + colL;
                float ds = dscale[e * H_ + col];
                #pragma unroll
                for (int i = 0; i < 4; ++i) {
                    #pragma unroll
                    for (int jj = 0; jj < 4; ++jj) {
                        int row = wr64 + i * 16 + q4 * 4 + jj;
                        SM[row * 136 + colL] = f2bf(acc[i][j][jj] * ds * swt[row]);
                    }
                }
            }
        }
        __syncthreads();
        #pragma unroll
        for (int v = 0; v < 4; ++v) {
            int rloc = tid & 127;
            int o = v * 4 + (tid >> 7);        // 0..15
            bf16x8 hv = *(const bf16x8*)&SM[rloc * 136 + o * 8];
            *(bf16x8*)(dscr + (size_t)(by * 128 + rloc) * H_
                       + bx * 256 + pass * 128 + o * 8) = hv;
        }
        __syncthreads();
    }
}

// ---------------- combine: out[t] = dscr[inv[2t]] + dscr[inv[2t+1]] ----------------
__global__ __launch_bounds__(256) void combine_kernel(
    const short* __restrict__ dscr, const int* __restrict__ inv,
    float* __restrict__ out) {
    int idx = blockIdx.x * 256 + threadIdx.x;   // 0 .. T*H/8-1
    int t = idx >> 9;
    int c8 = (idx & 511) * 8;
    int s0 = inv[t * 2], s1 = inv[t * 2 + 1];
    bf16x8 a = *(const bf16x8*)(dscr + (size_t)s0 * H_ + c8);
    bf16x8 b = *(const bf16x8*)(dscr + (size_t)s1 * H_ + c8);
    float4 o0, o1;
    o0.x = bf2f(a[0]) + bf2f(b[0]);
    o0.y = bf2f(a[1]) + bf2f(b[1]);
    o0.z = bf2f(a[2]) + bf2f(b[2]);
    o0.w = bf2f(a[3]) + bf2f(b[3]);
    o1.x = bf2f(a[4]) + bf2f(b[4]);
    o1.y = bf2f(a[5]) + bf2f(b[5]);
    o1.z = bf2f(a[6]) + bf2f(b[6]);
    o1.w = bf2f(a[7]) + bf2f(b[7]);
    *(float4*)(out + (size_t)t * H_ + c8) = o0;
    *(float4*)(out + (size_t)t * H_ + c8 + 4) = o1;
}

// ================= fallback path (fused int32 dequant, known-good) =================
__global__ __launch_bounds__(256) void gemm1_kernel(
    const float* __restrict__ x, const int* __restrict__ wq,
    const float* __restrict__ scale,
    const int* __restrict__ cnt, const int* __restrict__ off,
    const int* __restrict__ toks, short* __restrict__ h_ws) {
    int e = blockIdx.z;
    int cn = cnt[e];
    int row0 = blockIdx.y * 128;
    if (row0 >= cn) return;
    int base = off[e];
    int c0 = blockIdx.x * 64;
    __shared__ __align__(16) short As[4][128][8];
    __shared__ __align__(16) short Bg[4][64][8];
    __shared__ __align__(16) short Bu[4][64][8];
    __shared__ int stok[128];
    int tid = threadIdx.x;
    if (tid < 128) {
        int r = row0 + tid;
        stok[tid] = toks[base + (r < cn ? r : 0)];
    }
    __syncthreads();
    const int lane = tid & 63;
    const int wid = tid >> 6;
    const int wrow = (wid >> 1) * 64;
    const int wcc = (wid & 1) * 32;
    const int fr = lane & 15;
    const int kg = lane >> 4;
    f32x4 accg[4][2], accu[4][2];
    #pragma unroll
    for (int i = 0; i < 4; ++i)
        #pragma unroll
        for (int j = 0; j < 2; ++j) {
            accg[i][j] = f32x4{0.f, 0.f, 0.f, 0.f};
            accu[i][j] = f32x4{0.f, 0.f, 0.f, 0.f};
        }
    const int ar = tid & 127;
    const int akg = (tid >> 7) * 2;
    const int bc = tid & 63;
    const int bkg = (tid >> 6) & 3;
    const float* xrow = x + (size_t)stok[ar] * H_;
    const int* wg = wq + (size_t)e * H_ * TWOI_ + c0 + bc;
    const int* wu = wg + I_;
    for (int kk = 0; kk < H_; kk += 32) {
        {
            const float* xp = xrow + kk + akg * 8;
            #pragma unroll
            for (int p = 0; p < 2; ++p) {
                float4 f0 = *(const float4*)(xp + p * 8);
                float4 f1 = *(const float4*)(xp + p * 8 + 4);
                bf16x8 v;
                v[0] = f2bf(f0.x); v[1] = f2bf(f0.y); v[2] = f2bf(f0.z); v[3] = f2bf(f0.w);
                v[4] = f2bf(f1.x); v[5] = f2bf(f1.y); v[6] = f2bf(f1.z); v[7] = f2bf(f1.w);
                *(bf16x8*)&As[akg + p][ar][0] = v;
            }
        }
        {
            const int* wpg = wg + (size_t)(kk + bkg * 8) * TWOI_;
            const int* wpu = wu + (size_t)(kk + bkg * 8) * TWOI_;
            bf16x8 vg, vu;
            #pragma unroll
            for (int j = 0; j < 8; ++j) {
                vg[j] = f2bf((float)wpg[(size_t)j * TWOI_] - 128.f);
                vu[j] = f2bf((float)wpu[(size_t)j * TWOI_] - 128.f);
            }
            *(bf16x8*)&Bg[bkg][bc][0] = vg;
            *(bf16x8*)&Bu[bkg][bc][0] = vu;
        }
        __syncthreads();
        bf16x8 a[4], bg[2], bu[2];
        #pragma unroll
        for (int rf = 0; rf < 4; ++rf) a[rf] = *(const bf16x8*)&As[kg][wrow + rf * 16 + fr][0];
        #pragma unroll
        for (int cf = 0; cf < 2; ++cf) {
            bg[cf] = *(const bf16x8*)&Bg[kg][wcc + cf * 16 + fr][0];
            bu[cf] = *(const bf16x8*)&Bu[kg][wcc + cf * 16 + fr][0];
        }
        #pragma unroll
        for (int rf = 0; rf < 4; ++rf)
            #pragma unroll
            for (int cf = 0; cf < 2; ++cf) {
                accg[rf][cf] = __builtin_amdgcn_mfma_f32_16x16x32_bf16(a[rf], bg[cf], accg[rf][cf], 0, 0, 0);
                accu[rf][cf] = __builtin_amdgcn_mfma_f32_16x16x32_bf16(a[rf], bu[cf], accu[rf][cf], 0, 0, 0);
            }
        __syncthreads();
    }
    const int q4 = lane >> 4;
    #pragma unroll
    for (int cf = 0; cf < 2; ++cf) {
        int col = c0 + wcc + cf * 16 + fr;
        float gs = scale[e * TWOI_ + col];
        float us = scale[e * TWOI_ + I_ + col];
        #pragma unroll
        for (int rf = 0; rf < 4; ++rf) {
            #pragma unroll
            for (int j = 0; j < 4; ++j) {
                int row = wrow + rf * 16 + q4 * 4 + j;
                if (row0 + row < cn) {
                    float gv = accg[rf][cf][j] * gs;
                    float uv = accu[rf][cf][j] * us;
                    float s = 1.f / (1.f + __expf(-gv));
                    h_ws[(size_t)(base + row0 + row) * I_ + col] = f2bf(gv * s * uv);
                }
            }
        }
    }
}

__global__ __launch_bounds__(256) void gemm2_kernel(
    const short* __restrict__ h_ws, const int* __restrict__ wq,
    const float* __restrict__ dscale,
    const int* __restrict__ cnt, const int* __restrict__ off,
    const int* __restrict__ toks, const float* __restrict__ wts,
    float* __restrict__ out) {
    int e = blockIdx.z;
    int cn = cnt[e];
    int row0 = blockIdx.y * 128;
    if (row0 >= cn) return;
    int base = off[e];
    int c0 = blockIdx.x * 128;
    __shared__ __align__(16) short As[4][128][8];
    __shared__ __align__(16) short Bs[4][128][8];
    __shared__ int stok[128];
    __shared__ float swt[128];
    int tid = threadIdx.x;
    if (tid < 128) {
        int r = row0 + tid;
        int idx = base + (r < cn ? r : 0);
        stok[tid] = toks[idx];
        swt[tid] = (r < cn) ? wts[idx] : 0.f;
    }
    __syncthreads();
    const int lane = tid & 63;
    const int wid = tid >> 6;
    const int wrow = (wid >> 1) * 64;
    const int wcc = (wid & 1) * 64;
    const int fr = lane & 15;
    const int kg = lane >> 4;
    f32x4 acc[4][4];
    #pragma unroll
    for (int i = 0; i < 4; ++i)
        #pragma unroll
        for (int j = 0; j < 4; ++j) acc[i][j] = f32x4{0.f, 0.f, 0.f, 0.f};
    const int ar = tid & 127;
    const int akg = (tid >> 7) * 2;
    const int bc = tid & 127;
    const int bkg2 = (tid >> 7) * 2;
    const short* hrow = h_ws + (size_t)(base + ((row0 + ar) < cn ? row0 + ar : 0)) * I_;
    const int* wcol = wq + (size_t)e * I_ * H_ + c0 + bc;
    for (int kk = 0; kk < I_; kk += 32) {
        #pragma unroll
        for (int p = 0; p < 2; ++p) {
            *(bf16x8*)&As[akg + p][ar][0] = *(const bf16x8*)(hrow + kk + (akg + p) * 8);
        }
        #pragma unroll
        for (int p = 0; p < 2; ++p) {
            const int* wp = wcol + (size_t)(kk + (bkg2 + p) * 8) * H_;
            bf16x8 v;
            #pragma unroll
            for (int j = 0; j < 8; ++j) v[j] = f2bf((float)wp[(size_t)j * H_] - 128.f);
            *(bf16x8*)&Bs[bkg2 + p][bc][0] = v;
        }
        __syncthreads();
        bf16x8 a[4], b[4];
        #pragma unroll
        for (int rf = 0; rf < 4; ++rf) a[rf] = *(const bf16x8*)&As[kg][wrow + rf * 16 + fr][0];
        #pragma unroll
        for (int cf = 0; cf < 4; ++cf) b[cf] = *(const bf16x8*)&Bs[kg][wcc + cf * 16 + fr][0];
        #pragma unroll
        for (int rf = 0; rf < 4; ++rf)
            #pragma unroll
            for (int cf = 0; cf < 4; ++cf)
                acc[rf][cf] = __builtin_amdgcn_mfma_f32_16x16x32_bf16(a[rf], b[cf], acc[rf][cf], 0, 0, 0);
        __syncthreads();
    }
    const int q4 = lane >> 4;
    #pragma unroll
    for (int cf = 0; cf < 4; ++cf) {
        int col = c0 + wcc + cf * 16 + fr;
        float ds = dscale[e * H_ + col];
        #pragma unroll
        for (int rf = 0; rf < 4; ++rf) {
            #pragma unroll
            for (int j = 0; j < 4; ++j) {
                int row = wrow + rf * 16 + q4 * 4 + j;
                if (row0 + row < cn) {
                    float v = acc[rf][cf][j] * ds * swt[row];
                    atomicAdd(&out[(size_t)stok[row] * H_ + col], v);
                }
            }
        }
    }
}

extern "C" void kernel_launch(void* const* d_in, const int* in_sizes, int n_in,
                              void* d_out, int out_size, void* d_ws, size_t ws_size,
                              hipStream_t stream) {
    const float* x     = (const float*)d_in[0];
    const float* aff   = (const float*)d_in[1];
    const int*   guq   = (const int*)d_in[2];
    const float* gus   = (const float*)d_in[3];
    const int*   dwq   = (const int*)d_in[4];
    const float* dsc   = (const float*)d_in[5];
    const int*   eidx  = (const int*)d_in[6];
    float* out = (float*)d_out;

    char* ws = (char*)d_ws;
    int*   cnt  = (int*)ws;                      // 8
    int*   poff = cnt + 8;                       // 8
    int*   nrbG = cnt + 16;                      // 1
    int*   rbE  = cnt + 32;                      // 64
    int*   toks = (int*)(ws + 1024);             // 10240
    float* wts  = (float*)(ws + 1024 + NRBMAX_ * 256 * 4);
    int*   inv  = (int*)(ws + 1024 + NRBMAX_ * 256 * 8);   // 8192

    const size_t off_h  = (size_t)1 << 20;
    const size_t sz_h   = (size_t)NRBMAX_ * HPBLK_ * 2;     // 36.7 MB
    const size_t off_xg = off_h + sz_h;
    const size_t sz_xg  = (size_t)NRBMAX_ * XGBLK_ * 2;     // 83.9 MB (xg, reused as dscr)
    const size_t off_gu = off_xg + sz_xg;
    const size_t sz_gu  = (size_t)E_ * 512 * TWOI_ * 8 * 2; // 234.9 MB
    const size_t off_dn = off_gu + sz_gu;
    const size_t sz_dn  = (size_t)E_ * 224 * H_ * 8 * 2;    // 117.4 MB
    const size_t NEED   = off_dn + sz_dn;                   // ~474 MB

    short* h_pk = (short*)(ws + off_h);

    route_kernel<<<1, 1024, 0, stream>>>(eidx, aff, cnt, poff, rbE, nrbG, toks, wts, inv);

    if (ws_size >= NEED) {
        short* xg   = (short*)(ws + off_xg);    // also dscr after gemm1m
        short* wgur = (short*)(ws + off_gu);
        short* wdr  = (short*)(ws + off_dn);

        gather_x_kernel<<<NRBMAX_ * 8, 256, 0, stream>>>(x, toks, nrbG, xg);
        dim3 rg1(TWOI_ / 32, H_ / 64, E_);
        repack_gu_kernel<<<rg1, 256, 0, stream>>>(guq, wgur);
        dim3 rg2(H_ / 32, I_ / 64, E_);
        repack_dn_kernel<<<rg2, 256, 0, stream>>>(dwq, wdr);

        gemm1m_kernel<<<14 * NRBMAX_ * 2, 512, 0, stream>>>(xg, wgur, gus, rbE, nrbG, h_pk);
        // xg dead; reuse as dscr
        gemm2m_kernel<<<16 * NRBMAX_ * 2, 512, 0, stream>>>(h_pk, wdr, dsc, rbE, nrbG, wts, xg);
        combine_kernel<<<(T_ * H_ / 8) / 256, 256, 0, stream>>>(xg, inv, out);
    } else {
        hipMemsetAsync(d_out, 0, (size_t)out_size * sizeof(float), stream);
        dim3 g1(I_ / 64, NSLOT_ / 128, E_);
        gemm1_kernel<<<g1, 256, 0, stream>>>(x, guq, gus, cnt, poff, toks, h_pk);
        dim3 g2(H_ / 128, NSLOT_ / 128, E_);
        gemm2_kernel<<<g2, 256, 0, stream>>>(h_pk, dwq, dsc, cnt, poff, toks, wts, out);
    }
}

// Round 13
// 627.528 us; speedup vs baseline: 1.3740x; 1.3241x over previous
//
#include <hip/hip_runtime.h>
#include <hip/hip_bf16.h>
#include <stdint.h>

#define E_ 8
#define H_ 4096
#define I_ 1792
#define TWOI_ 3584
#define T_ 4096
#define NSLOT_ 8192
#define NRBMAX_ 40        /* max padded 256-slot blocks */
#define XG8BLK_ 1048576   /* bytes per xg8 slot-block: 256kp*256row*16 */
#define HPBLK_ 458752     /* shorts per h_pk slot-block: 224*256*8 */

typedef __attribute__((ext_vector_type(4))) float f32x4;
typedef __attribute__((ext_vector_type(8))) short bf16x8;
typedef __attribute__((ext_vector_type(4))) int i32x4;

static __device__ __forceinline__ short f2bf(float f) {
    unsigned u = __builtin_bit_cast(unsigned, f);
    u += 0x7FFF + ((u >> 16) & 1);   // round-to-nearest-even
    return (short)(u >> 16);
}

static __device__ __forceinline__ float bf2f(short s) {
    unsigned u = ((unsigned)(unsigned short)s) << 16;
    return __builtin_bit_cast(float, u);
}

static __device__ __forceinline__ void gld16(const void* g, void* l) {
    __builtin_amdgcn_global_load_lds(
        (const __attribute__((address_space(1))) void*)g,
        (__attribute__((address_space(3))) void*)l, 16, 0, 0);
}

// ---------------- routing: padded per-expert lists + row-block table ----------------
__global__ void route_kernel(const int* __restrict__ eidx,
                             const float* __restrict__ aff,
                             int* __restrict__ cnt, int* __restrict__ poff,
                             int* __restrict__ rbE, int* __restrict__ nrbG,
                             int* __restrict__ toks, float* __restrict__ wts,
                             int* __restrict__ inv) {
    __shared__ int scnt[E_];
    __shared__ int spoff[E_];
    __shared__ int scur[E_];
    int tid = threadIdx.x;
    if (tid < E_) scnt[tid] = 0;
    __syncthreads();
    for (int s = tid; s < NSLOT_; s += blockDim.x) {
        atomicAdd(&scnt[eidx[s]], 1);
    }
    __syncthreads();
    if (tid == 0) {
        int acc = 0, rb = 0;
        for (int e = 0; e < E_; ++e) {
            int c = scnt[e];
            cnt[e] = c; poff[e] = acc; spoff[e] = acc;
            int nb = (c + 255) >> 8;
            for (int i = 0; i < nb; ++i) rbE[rb++] = e;
            acc += nb << 8;
        }
        *nrbG = rb;
        for (int i = rb; i < NRBMAX_; ++i) rbE[i] = -1;
    }
    __syncthreads();
    if (tid < E_) scur[tid] = spoff[tid];
    __syncthreads();
    for (int s = tid; s < NSLOT_; s += blockDim.x) {
        int t = s >> 1;
        int e0 = eidx[t * 2], e1 = eidx[t * 2 + 1];
        float a0 = aff[t * E_ + e0], a1 = aff[t * E_ + e1];
        int k = s & 1;
        int e = k ? e1 : e0;
        float w = (k ? a1 : a0) / (a0 + a1);
        int pos = atomicAdd(&scur[e], 1);
        toks[pos] = t;
        wts[pos] = w;
        inv[s] = pos;
    }
    __syncthreads();
    for (int e = 0; e < E_; ++e) {
        int c = scnt[e];
        if (c == 0) continue;
        int padded = ((c + 255) >> 8) << 8;
        int lastTok = toks[spoff[e] + c - 1];
        for (int p = c + tid; p < padded; p += blockDim.x) {
            toks[spoff[e] + p] = lastTok;
            wts[spoff[e] + p] = 0.f;
        }
    }
}

// ---------------- per-token abs-max of x -> quant/dequant scales ----------------
__global__ __launch_bounds__(256) void xmax_kernel(const float* __restrict__ x,
                                                   float* __restrict__ qsx,
                                                   float* __restrict__ sxf) {
    int t = blockIdx.x * 4 + (threadIdx.x >> 6);
    int lane = threadIdx.x & 63;
    const float* p = x + (size_t)t * H_;
    float m = 0.f;
    #pragma unroll
    for (int i = 0; i < 16; ++i) {
        float4 v = *(const float4*)(p + (i * 64 + lane) * 4);
        m = fmaxf(m, fmaxf(fmaxf(fabsf(v.x), fabsf(v.y)), fmaxf(fabsf(v.z), fabsf(v.w))));
    }
    #pragma unroll
    for (int off = 32; off > 0; off >>= 1) m = fmaxf(m, __shfl_xor(m, off));
    if (lane == 0) {
        sxf[t] = (m > 0.f) ? m / 127.f : 0.f;
        qsx[t] = (m > 0.f) ? 127.f / m : 0.f;
    }
}

// ---------------- gather x -> int8 k-packet xg8[sb][256 kp][256 row][16] ----------------
__global__ __launch_bounds__(256) void gather_x8_kernel(const float* __restrict__ x,
                                                        const int* __restrict__ toks,
                                                        const float* __restrict__ qsx,
                                                        const float* __restrict__ sxf,
                                                        const int* __restrict__ nrbG,
                                                        char* __restrict__ xg8,
                                                        float* __restrict__ ssx) {
    int blk = blockIdx.x >> 3;        // 0..39
    if (blk >= *nrbG) return;
    int sc = blockIdx.x & 7;          // 32-kp chunk
    int row = threadIdx.x;            // 0..255
    int g = blk * 256 + row;
    int t = toks[g];
    if (sc == 0) ssx[g] = sxf[t];
    float q = qsx[t];
    const float* src = x + (size_t)t * H_ + sc * 512;
    char* dst = xg8 + (size_t)blk * XG8BLK_ + (size_t)row * 16;
    for (int kp = 0; kp < 32; ++kp) {
        int w[4];
        #pragma unroll
        for (int d = 0; d < 4; ++d) {
            float4 v = *(const float4*)(src + kp * 16 + d * 4);
            int b0 = (int)rintf(fmaxf(-127.f, fminf(127.f, v.x * q)));
            int b1 = (int)rintf(fmaxf(-127.f, fminf(127.f, v.y * q)));
            int b2 = (int)rintf(fmaxf(-127.f, fminf(127.f, v.z * q)));
            int b3 = (int)rintf(fmaxf(-127.f, fminf(127.f, v.w * q)));
            w[d] = (b0 & 255) | ((b1 & 255) << 8) | ((b2 & 255) << 16) | ((b3 & 255) << 24);
        }
        *(int4*)(dst + (size_t)(sc * 32 + kp) * 4096) = make_int4(w[0], w[1], w[2], w[3]);
    }
}

// ---------------- repack gate_up -> int8 (q-128), k-packet, g/u 16-col interleave ----------------
// out[e][kp=k/16][rc 3584][16]; rc: chunk=rc>>4, m=chunk>>1, orig=(chunk&1?I_:0)+m*16+(rc&15)
__global__ __launch_bounds__(256) void repack_gu8_kernel(const int* __restrict__ wq,
                                                         char* __restrict__ out) {
    __shared__ char sm[64][68];
    int e = blockIdx.z;
    int byk = blockIdx.y;             // 0..63 (64 k-rows each)
    int bxg = blockIdx.x;             // 0..55 (64 repacked cols each)
    int tid = threadIdx.x;
    {
        int rw = tid >> 2;            // 0..63
        int q = tid & 3;              // 16-col group
        int rc0 = bxg * 64 + q * 16;
        int chunk = rc0 >> 4;
        int orig0 = ((chunk & 1) ? I_ : 0) + (chunk >> 1) * 16;
        const int* src = wq + ((size_t)e * H_ + byk * 64 + rw) * TWOI_ + orig0;
        #pragma unroll
        for (int i = 0; i < 16; ++i)
            sm[rw][q * 16 + i] = (char)(src[i] - 128);
    }
    __syncthreads();
    {
        int kp_l = tid >> 6;          // 0..3
        int c = tid & 63;
        int w[4];
        #pragma unroll
        for (int d = 0; d < 4; ++d) {
            int b0 = sm[kp_l * 16 + d * 4 + 0][c] & 255;
            int b1 = sm[kp_l * 16 + d * 4 + 1][c] & 255;
            int b2 = sm[kp_l * 16 + d * 4 + 2][c] & 255;
            int b3 = sm[kp_l * 16 + d * 4 + 3][c] & 255;
            w[d] = b0 | (b1 << 8) | (b2 << 16) | (b3 << 24);
        }
        size_t off = (((size_t)e * 256 + byk * 4 + kp_l) * TWOI_ + bxg * 64 + c) * 16;
        *(int4*)(out + off) = make_int4(w[0], w[1], w[2], w[3]);
    }
}

// ---------------- repack down -> bf16 k-packet (unchanged format) ----------------
__global__ __launch_bounds__(256) void repack_dn_kernel(const int* __restrict__ wq,
                                                        short* __restrict__ out) {
    __shared__ short sm[64][33];
    int e = blockIdx.z;
    int by = blockIdx.y;              // 0..27
    int bx = blockIdx.x;              // 0..127
    int tid = threadIdx.x;
    {
        int rw = tid >> 2;
        int q = tid & 3;
        const int* src = wq + ((size_t)e * I_ + by * 64 + rw) * H_ + bx * 32 + q * 8;
        #pragma unroll
        for (int i = 0; i < 8; ++i)
            sm[rw][q * 8 + i] = f2bf((float)(src[i] - 128));
    }
    __syncthreads();
    {
        int yl = tid >> 5;
        int c = tid & 31;
        bf16x8 v;
        #pragma unroll
        for (int i = 0; i < 8; ++i) v[i] = sm[yl * 8 + i][c];
        *(bf16x8*)(out + (((size_t)e * 224 + by * 8 + yl) * H_ + bx * 32 + c) * 8) = v;
    }
}

// ==================== GEMM1 int8: BM=128 BN=256 BK=128, 48KB LDS, 2 blk/CU ====================
__global__ __launch_bounds__(512, 4) void gemm1i_kernel(
    const char* __restrict__ xg8,       // [sb][256kp][256][16] i8
    const char* __restrict__ wgu8,      // [e][256kp][3584][16] i8
    const float* __restrict__ scale,    // [E,2I]
    const float* __restrict__ ssx,      // per-slot x dequant scale
    const int* __restrict__ rbE, const int* __restrict__ nrbG,
    short* __restrict__ h_pk) {         // bf16 k-packet h [sb][224][256][8]
    // sb-major decode, halves paired per bx (B panel L2-hit)
    const int xcd = blockIdx.x & 7;
    const int loc = blockIdx.x >> 3;          // 0..139
    const int work = xcd * 140 + loc;         // 0..1119
    const int sb = work / 28;                 // 0..39
    const int l28 = work % 28;
    const int bxg = l28 >> 1;                 // 0..13
    const int half = l28 & 1;
    if (sb >= *nrbG) return;
    const int e = rbE[sb];

    __shared__ __align__(16) char SM8[49152];   // A:[0,16384) B:[16384,49152)
    __shared__ float sxs[128];

    int tid = threadIdx.x;
    if (tid < 128) sxs[tid] = ssx[sb * 256 + half * 128 + tid];

    const int lane = tid & 63;
    const int wid = tid >> 6;
    const int wr64 = (wid >> 2) * 64;
    const int wc64 = (wid & 3) * 64;
    const int fr = lane & 15;
    const int kq = lane >> 4;

    const int arow = tid & 127;
    const int akg = tid >> 7;                  // 0..3 (+4)
    const int bcol = tid & 255;
    const int bkg = tid >> 8;                  // 0..1

    const char* asrc = xg8 + (size_t)sb * XG8BLK_ + (size_t)(half * 128 + arow) * 16;
    const char* bbase = wgu8 + (size_t)e * (256ull * TWOI_ * 16) + (size_t)(bxg * 256 + bcol) * 16;

    i32x4 acc[4][4];
    #pragma unroll
    for (int i = 0; i < 4; ++i)
        #pragma unroll
        for (int j = 0; j < 4; ++j) acc[i][j] = i32x4{0, 0, 0, 0};

    for (int st = 0; st < 32; ++st) {
        #pragma unroll
        for (int p = 0; p < 2; ++p) {
            const int kg = akg + p * 4;
            gld16(asrc + (size_t)(st * 8 + kg) * 4096, &SM8[(kg * 128 + arow) * 16]);
        }
        #pragma unroll
        for (int p = 0; p < 4; ++p) {
            const int kg = bkg * 4 + p;
            gld16(bbase + (size_t)(st * 8 + kg) * (TWOI_ * 16), &SM8[16384 + (kg * 256 + bcol) * 16]);
        }
        __syncthreads();
        #pragma unroll
        for (int s = 0; s < 2; ++s) {
            const int kgq = s * 4 + kq;
            i32x4 av[4], bv[4];
            #pragma unroll
            for (int i = 0; i < 4; ++i)
                av[i] = *(const i32x4*)&SM8[(kgq * 128 + wr64 + i * 16 + fr) * 16];
            #pragma unroll
            for (int j = 0; j < 4; ++j)
                bv[j] = *(const i32x4*)&SM8[16384 + (kgq * 256 + wc64 + j * 16 + fr) * 16];
            #pragma unroll
            for (int i = 0; i < 4; ++i)
                #pragma unroll
                for (int j = 0; j < 4; ++j)
                    acc[i][j] = __builtin_amdgcn_mfma_i32_16x16x64_i8(av[i], bv[j], acc[i][j], 0, 0, 0);
        }
        __syncthreads();
    }

    // ---- epilogue: dequant + silu(g)*u -> LDS transpose -> bf16 k-packet h_pk ----
    short* SMs = (short*)SM8;
    const int q4 = lane >> 4;
    #pragma unroll
    for (int cfp = 0; cfp < 2; ++cfp) {
        int ml = (wid & 3) * 2 + cfp;          // local 16-col h block 0..7
        int hcol = (bxg * 8 + ml) * 16 + fr;
        float gs = scale[e * TWOI_ + hcol];
        float us = scale[e * TWOI_ + I_ + hcol];
        int cl = ml * 16 + fr;                 // 0..127
        #pragma unroll
        for (int i = 0; i < 4; ++i) {
            #pragma unroll
            for (int jj = 0; jj < 4; ++jj) {
                int row = wr64 + i * 16 + q4 * 4 + jj;
                float sx = sxs[row];
                float gv = (float)acc[i][cfp * 2][jj] * sx * gs;
                float uv = (float)acc[i][cfp * 2 + 1][jj] * sx * us;
                float sg = 1.f / (1.f + __expf(-gv));
                SMs[row * 136 + cl] = f2bf(gv * sg * uv);
            }
        }
    }
    __syncthreads();
    #pragma unroll
    for (int v = 0; v < 4; ++v) {
        int rloc = tid & 127;
        int o = v * 4 + (tid >> 7);            // 0..15
        bf16x8 hv = *(const bf16x8*)&SMs[rloc * 136 + o * 8];
        *(bf16x8*)(h_pk + (size_t)sb * HPBLK_
                   + (size_t)(bxg * 16 + o) * 2048
                   + (size_t)(half * 128 + rloc) * 8) = hv;
    }
}

// ==================== GEMM2 bf16 m97-style: BM=128 BN=256 BK=64, sb-major ====================
__global__ __launch_bounds__(512, 4) void gemm2m_kernel(
    const short* __restrict__ h_pk,     // [sb][224][256][8] bf16
    const short* __restrict__ wd,       // [e][224][4096][8] bf16
    const float* __restrict__ dscale,   // [E,H]
    const int* __restrict__ rbE, const int* __restrict__ nrbG,
    const float* __restrict__ wts,
    short* __restrict__ dscr) {         // [padded slots, H] bf16
    const int xcd = blockIdx.x & 7;
    const int loc = blockIdx.x >> 3;          // 0..159
    const int work = xcd * 160 + loc;         // 0..1279
    const int sb = work / 32;                 // 0..39
    const int l32 = work % 32;
    const int bx = l32 >> 1;                  // 0..15
    const int half = l32 & 1;
    if (sb >= *nrbG) return;
    const int e = rbE[sb];

    __shared__ __align__(16) short SM[24576];
    __shared__ float swt[128];

    int tid = threadIdx.x;
    if (tid < 128) swt[tid] = wts[sb * 256 + half * 128 + tid];
    __syncthreads();

    const int lane = tid & 63;
    const int wid = tid >> 6;
    const int wr64 = (wid >> 2) * 64;
    const int wc64 = (wid & 3) * 64;
    const int fr = lane & 15;
    const int kq = lane >> 4;

    const int arow = tid & 127;
    const int akg = tid >> 7;
    const int bcol = tid & 255;
    const int bkg = tid >> 8;

    const size_t asrc0 = (size_t)sb * HPBLK_ + (size_t)(half * 128 + arow) * 8;
    const size_t bstr = (size_t)H_ * 8;
    const short* bbase = wd + (size_t)e * 224 * bstr + (size_t)(bx * 256 + bcol) * 8;

    f32x4 acc[4][4];
    #pragma unroll
    for (int i = 0; i < 4; ++i)
        #pragma unroll
        for (int j = 0; j < 4; ++j) acc[i][j] = f32x4{0.f, 0.f, 0.f, 0.f};

    for (int st = 0; st < 28; ++st) {
        #pragma unroll
        for (int p = 0; p < 2; ++p) {
            const int kg = akg + p * 4;
            gld16(h_pk + asrc0 + (size_t)(st * 8 + kg) * 2048, &SM[(kg * 128 + arow) * 8]);
        }
        #pragma unroll
        for (int p = 0; p < 4; ++p) {
            const int kg = bkg * 4 + p;
            gld16(bbase + (size_t)(st * 8 + kg) * bstr, &SM[8192 + (kg * 256 + bcol) * 8]);
        }
        __syncthreads();
        #pragma unroll
        for (int s = 0; s < 2; ++s) {
            const int kgq = s * 4 + kq;
            bf16x8 av[4], bv[4];
            #pragma unroll
            for (int i = 0; i < 4; ++i)
                av[i] = *(const bf16x8*)&SM[(kgq * 128 + wr64 + i * 16 + fr) * 8];
            #pragma unroll
            for (int j = 0; j < 4; ++j)
                bv[j] = *(const bf16x8*)&SM[8192 + (kgq * 256 + wc64 + j * 16 + fr) * 8];
            #pragma unroll
            for (int i = 0; i < 4; ++i)
                #pragma unroll
                for (int j = 0; j < 4; ++j)
                    acc[i][j] = __builtin_amdgcn_mfma_f32_16x16x32_bf16(av[i], bv[j], acc[i][j], 0, 0, 0);
        }
        __syncthreads();
    }

    const int q4 = lane >> 4;
    const int wn = wid & 3;
    const int row0 = sb * 256 + half * 128;
    #pragma unroll
    for (int pass = 0; pass < 2; ++pass) {
        if ((wn >> 1) == pass) {
            #pragma unroll
            for (int j = 0; j < 4; ++j) {
                int colL = (wn & 1) * 64 + j * 16 + fr;        // 0..127
                int col = bx * 256 + pass * 128 + colL;
                float ds = dscale[e * H_ + col];
                #pragma unroll
                for (int i = 0; i < 4; ++i) {
                    #pragma unroll
                    for (int jj = 0; jj < 4; ++jj) {
                        int row = wr64 + i * 16 + q4 * 4 + jj;
                        SM[row * 136 + colL] = f2bf(acc[i][j][jj] * ds * swt[row]);
                    }
                }
            }
        }
        __syncthreads();
        #pragma unroll
        for (int v = 0; v < 4; ++v) {
            int rloc = tid & 127;
            int o = v * 4 + (tid >> 7);        // 0..15
            bf16x8 hv = *(const bf16x8*)&SM[rloc * 136 + o * 8];
            *(bf16x8*)(dscr + (size_t)(row0 + rloc) * H_
                       + bx * 256 + pass * 128 + o * 8) = hv;
        }
        __syncthreads();
    }
}

// ---------------- combine: out[t] = dscr[inv[2t]] + dscr[inv[2t+1]] ----------------
__global__ __launch_bounds__(256) void combine_kernel(
    const short* __restrict__ dscr, const int* __restrict__ inv,
    float* __restrict__ out) {
    int idx = blockIdx.x * 256 + threadIdx.x;
    int t = idx >> 9;
    int c8 = (idx & 511) * 8;
    int s0 = inv[t * 2], s1 = inv[t * 2 + 1];
    bf16x8 a = *(const bf16x8*)(dscr + (size_t)s0 * H_ + c8);
    bf16x8 b = *(const bf16x8*)(dscr + (size_t)s1 * H_ + c8);
    float4 o0, o1;
    o0.x = bf2f(a[0]) + bf2f(b[0]);
    o0.y = bf2f(a[1]) + bf2f(b[1]);
    o0.z = bf2f(a[2]) + bf2f(b[2]);
    o0.w = bf2f(a[3]) + bf2f(b[3]);
    o1.x = bf2f(a[4]) + bf2f(b[4]);
    o1.y = bf2f(a[5]) + bf2f(b[5]);
    o1.z = bf2f(a[6]) + bf2f(b[6]);
    o1.w = bf2f(a[7]) + bf2f(b[7]);
    *(float4*)(out + (size_t)t * H_ + c8) = o0;
    *(float4*)(out + (size_t)t * H_ + c8 + 4) = o1;
}

// ================= fallback path (fused int32 dequant, known-good) =================
__global__ __launch_bounds__(256) void gemm1_kernel(
    const float* __restrict__ x, const int* __restrict__ wq,
    const float* __restrict__ scale,
    const int* __restrict__ cnt, const int* __restrict__ off,
    const int* __restrict__ toks, short* __restrict__ h_ws) {
    int e = blockIdx.z;
    int cn = cnt[e];
    int row0 = blockIdx.y * 128;
    if (row0 >= cn) return;
    int base = off[e];
    int c0 = blockIdx.x * 64;
    __shared__ __align__(16) short As[4][128][8];
    __shared__ __align__(16) short Bg[4][64][8];
    __shared__ __align__(16) short Bu[4][64][8];
    __shared__ int stok[128];
    int tid = threadIdx.x;
    if (tid < 128) {
        int r = row0 + tid;
        stok[tid] = toks[base + (r < cn ? r : 0)];
    }
    __syncthreads();
    const int lane = tid & 63;
    const int wid = tid >> 6;
    const int wrow = (wid >> 1) * 64;
    const int wcc = (wid & 1) * 32;
    const int fr = lane & 15;
    const int kg = lane >> 4;
    f32x4 accg[4][2], accu[4][2];
    #pragma unroll
    for (int i = 0; i < 4; ++i)
        #pragma unroll
        for (int j = 0; j < 2; ++j) {
            accg[i][j] = f32x4{0.f, 0.f, 0.f, 0.f};
            accu[i][j] = f32x4{0.f, 0.f, 0.f, 0.f};
        }
    const int ar = tid & 127;
    const int akg = (tid >> 7) * 2;
    const int bc = tid & 63;
    const int bkg = (tid >> 6) & 3;
    const float* xrow = x + (size_t)stok[ar] * H_;
    const int* wg = wq + (size_t)e * H_ * TWOI_ + c0 + bc;
    const int* wu = wg + I_;
    for (int kk = 0; kk < H_; kk += 32) {
        {
            const float* xp = xrow + kk + akg * 8;
            #pragma unroll
            for (int p = 0; p < 2; ++p) {
                float4 f0 = *(const float4*)(xp + p * 8);
                float4 f1 = *(const float4*)(xp + p * 8 + 4);
                bf16x8 v;
                v[0] = f2bf(f0.x); v[1] = f2bf(f0.y); v[2] = f2bf(f0.z); v[3] = f2bf(f0.w);
                v[4] = f2bf(f1.x); v[5] = f2bf(f1.y); v[6] = f2bf(f1.z); v[7] = f2bf(f1.w);
                *(bf16x8*)&As[akg + p][ar][0] = v;
            }
        }
        {
            const int* wpg = wg + (size_t)(kk + bkg * 8) * TWOI_;
            const int* wpu = wu + (size_t)(kk + bkg * 8) * TWOI_;
            bf16x8 vg, vu;
            #pragma unroll
            for (int j = 0; j < 8; ++j) {
                vg[j] = f2bf((float)wpg[(size_t)j * TWOI_] - 128.f);
                vu[j] = f2bf((float)wpu[(size_t)j * TWOI_] - 128.f);
            }
            *(bf16x8*)&Bg[bkg][bc][0] = vg;
            *(bf16x8*)&Bu[bkg][bc][0] = vu;
        }
        __syncthreads();
        bf16x8 a[4], bg[2], bu[2];
        #pragma unroll
        for (int rf = 0; rf < 4; ++rf) a[rf] = *(const bf16x8*)&As[kg][wrow + rf * 16 + fr][0];
        #pragma unroll
        for (int cf = 0; cf < 2; ++cf) {
            bg[cf] = *(const bf16x8*)&Bg[kg][wcc + cf * 16 + fr][0];
            bu[cf] = *(const bf16x8*)&Bu[kg][wcc + cf * 16 + fr][0];
        }
        #pragma unroll
        for (int rf = 0; rf < 4; ++rf)
            #pragma unroll
            for (int cf = 0; cf < 2; ++cf) {
                accg[rf][cf] = __builtin_amdgcn_mfma_f32_16x16x32_bf16(a[rf], bg[cf], accg[rf][cf], 0, 0, 0);
                accu[rf][cf] = __builtin_amdgcn_mfma_f32_16x16x32_bf16(a[rf], bu[cf], accu[rf][cf], 0, 0, 0);
            }
        __syncthreads();
    }
    const int q4 = lane >> 4;
    #pragma unroll
    for (int cf = 0; cf < 2; ++cf) {
        int col = c0 + wcc + cf * 16 + fr;
        float gs = scale[e * TWOI_ + col];
        float us = scale[e * TWOI_ + I_ + col];
        #pragma unroll
        for (int rf = 0; rf < 4; ++rf) {
            #pragma unroll
            for (int j = 0; j < 4; ++j) {
                int row = wrow + rf * 16 + q4 * 4 + j;
                if (row0 + row < cn) {
                    float gv = accg[rf][cf][j] * gs;
                    float uv = accu[rf][cf][j] * us;
                    float s = 1.f / (1.f + __expf(-gv));
                    h_ws[(size_t)(base + row0 + row) * I_ + col] = f2bf(gv * s * uv);
                }
            }
        }
    }
}

__global__ __launch_bounds__(256) void gemm2_kernel(
    const short* __restrict__ h_ws, const int* __restrict__ wq,
    const float* __restrict__ dscale,
    const int* __restrict__ cnt, const int* __restrict__ off,
    const int* __restrict__ toks, const float* __restrict__ wts,
    float* __restrict__ out) {
    int e = blockIdx.z;
    int cn = cnt[e];
    int row0 = blockIdx.y * 128;
    if (row0 >= cn) return;
    int base = off[e];
    int c0 = blockIdx.x * 128;
    __shared__ __align__(16) short As[4][128][8];
    __shared__ __align__(16) short Bs[4][128][8];
    __shared__ int stok[128];
    __shared__ float swt[128];
    int tid = threadIdx.x;
    if (tid < 128) {
        int r = row0 + tid;
        int idx = base + (r < cn ? r : 0);
        stok[tid] = toks[idx];
        swt[tid] = (r < cn) ? wts[idx] : 0.f;
    }
    __syncthreads();
    const int lane = tid & 63;
    const int wid = tid >> 6;
    const int wrow = (wid >> 1) * 64;
    const int wcc = (wid & 1) * 64;
    const int fr = lane & 15;
    const int kg = lane >> 4;
    f32x4 acc[4][4];
    #pragma unroll
    for (int i = 0; i < 4; ++i)
        #pragma unroll
        for (int j = 0; j < 4; ++j) acc[i][j] = f32x4{0.f, 0.f, 0.f, 0.f};
    const int ar = tid & 127;
    const int akg = (tid >> 7) * 2;
    const int bc = tid & 127;
    const int bkg2 = (tid >> 7) * 2;
    const short* hrow = h_ws + (size_t)(base + ((row0 + ar) < cn ? row0 + ar : 0)) * I_;
    const int* wcol = wq + (size_t)e * I_ * H_ + c0 + bc;
    for (int kk = 0; kk < I_; kk += 32) {
        #pragma unroll
        for (int p = 0; p < 2; ++p) {
            *(bf16x8*)&As[akg + p][ar][0] = *(const bf16x8*)(hrow + kk + (akg + p) * 8);
        }
        #pragma unroll
        for (int p = 0; p < 2; ++p) {
            const int* wp = wcol + (size_t)(kk + (bkg2 + p) * 8) * H_;
            bf16x8 v;
            #pragma unroll
            for (int j = 0; j < 8; ++j) v[j] = f2bf((float)wp[(size_t)j * H_] - 128.f);
            *(bf16x8*)&Bs[bkg2 + p][bc][0] = v;
        }
        __syncthreads();
        bf16x8 a[4], b[4];
        #pragma unroll
        for (int rf = 0; rf < 4; ++rf) a[rf] = *(const bf16x8*)&As[kg][wrow + rf * 16 + fr][0];
        #pragma unroll
        for (int cf = 0; cf < 4; ++cf) b[cf] = *(const bf16x8*)&Bs[kg][wcc + cf * 16 + fr][0];
        #pragma unroll
        for (int rf = 0; rf < 4; ++rf)
            #pragma unroll
            for (int cf = 0; cf < 4; ++cf)
                acc[rf][cf] = __builtin_amdgcn_mfma_f32_16x16x32_bf16(a[rf], b[cf], acc[rf][cf], 0, 0, 0);
        __syncthreads();
    }
    const int q4 = lane >> 4;
    #pragma unroll
    for (int cf = 0; cf < 4; ++cf) {
        int col = c0 + wcc + cf * 16 + fr;
        float ds = dscale[e * H_ + col];
        #pragma unroll
        for (int rf = 0; rf < 4; ++rf) {
            #pragma unroll
            for (int j = 0; j < 4; ++j) {
                int row = wrow + rf * 16 + q4 * 4 + j;
                if (row0 + row < cn) {
                    float v = acc[rf][cf][j] * ds * swt[row];
                    atomicAdd(&out[(size_t)stok[row] * H_ + col], v);
                }
            }
        }
    }
}

extern "C" void kernel_launch(void* const* d_in, const int* in_sizes, int n_in,
                              void* d_out, int out_size, void* d_ws, size_t ws_size,
                              hipStream_t stream) {
    const float* x     = (const float*)d_in[0];
    const float* aff   = (const float*)d_in[1];
    const int*   guq   = (const int*)d_in[2];
    const float* gus   = (const float*)d_in[3];
    const int*   dwq   = (const int*)d_in[4];
    const float* dsc   = (const float*)d_in[5];
    const int*   eidx  = (const int*)d_in[6];
    float* out = (float*)d_out;

    char* ws = (char*)d_ws;
    int*   cnt  = (int*)ws;                      // 8
    int*   poff = cnt + 8;                       // 8
    int*   nrbG = cnt + 16;                      // 1
    int*   rbE  = cnt + 32;                      // 64
    int*   toks = (int*)(ws + 1024);             // 10240 ints
    float* wts  = (float*)(ws + 1024 + 40960);
    int*   inv  = (int*)(ws + 1024 + 81920);     // 8192 ints
    float* qsx  = (float*)(ws + 1024 + 114688);  // T floats
    float* sxf  = (float*)(ws + 1024 + 131072);  // T floats
    float* ssx  = (float*)(ws + 1024 + 147456);  // 10240 floats

    const size_t off_h   = (size_t)1 << 20;
    const size_t sz_h    = (size_t)NRBMAX_ * HPBLK_ * 2;     // 36.7 MB (h_pk bf16)
    const size_t off_xg8 = off_h + sz_h;
    const size_t sz_xg8  = (size_t)NRBMAX_ * XG8BLK_;        // 41.9 MB (i8)
    const size_t off_ds  = off_xg8 + sz_xg8;
    const size_t sz_ds   = (size_t)NRBMAX_ * 256 * H_ * 2;   // 83.9 MB (dscr bf16)
    const size_t off_gu8 = off_ds + sz_ds;
    const size_t sz_gu8  = (size_t)E_ * 256 * TWOI_ * 16;    // 117.4 MB (i8)
    const size_t off_dn  = off_gu8 + sz_gu8;
    const size_t sz_dn   = (size_t)E_ * 224 * H_ * 8 * 2;    // 117.4 MB (bf16)
    const size_t NEED    = off_dn + sz_dn;                   // ~399 MB

    short* h_pk = (short*)(ws + off_h);

    route_kernel<<<1, 1024, 0, stream>>>(eidx, aff, cnt, poff, rbE, nrbG, toks, wts, inv);

    if (ws_size >= NEED) {
        char*  xg8  = ws + off_xg8;
        short* dscr = (short*)(ws + off_ds);
        char*  wgu8 = ws + off_gu8;
        short* wdr  = (short*)(ws + off_dn);

        xmax_kernel<<<T_ / 4, 256, 0, stream>>>(x, qsx, sxf);
        gather_x8_kernel<<<NRBMAX_ * 8, 256, 0, stream>>>(x, toks, qsx, sxf, nrbG, xg8, ssx);
        dim3 rg1(TWOI_ / 64, H_ / 64, E_);
        repack_gu8_kernel<<<rg1, 256, 0, stream>>>(guq, wgu8);
        dim3 rg2(H_ / 32, I_ / 64, E_);
        repack_dn_kernel<<<rg2, 256, 0, stream>>>(dwq, wdr);

        gemm1i_kernel<<<14 * NRBMAX_ * 2, 512, 0, stream>>>(xg8, wgu8, gus, ssx, rbE, nrbG, h_pk);
        gemm2m_kernel<<<16 * NRBMAX_ * 2, 512, 0, stream>>>(h_pk, wdr, dsc, rbE, nrbG, wts, dscr);
        combine_kernel<<<(T_ * H_ / 8) / 256, 256, 0, stream>>>(dscr, inv, out);
    } else {
        hipMemsetAsync(d_out, 0, (size_t)out_size * sizeof(float), stream);
        dim3 g1(I_ / 64, NSLOT_ / 128, E_);
        gemm1_kernel<<<g1, 256, 0, stream>>>(x, guq, gus, cnt, poff, toks, h_pk);
        dim3 g2(H_ / 128, NSLOT_ / 128, E_);
        gemm2_kernel<<<g2, 256, 0, stream>>>(h_pk, dwq, dsc, cnt, poff, toks, wts, out);
    }
}